// Round 5
// baseline (103.223 us; speedup 1.0000x reference)
//
#include <hip/hip_runtime.h>

namespace {

constexpr int D_DIM   = 512;
constexpr int ENT_LEN = 39;
constexpr int N_MOVES = 896;

typedef __attribute__((ext_vector_type(4))) float f32x4;
typedef __attribute__((ext_vector_type(2))) float f32x2;

// ---- fused bf16 table row offsets (rows of 512 bf16 = 1 KB each) ----
constexpr int R_SP    = 0;                 // 1280 rows: W_species[r] + sum(all 9 biases)
constexpr int R_AB    = 1280;              // 320
constexpr int R_IT    = 1600;              // 1024
constexpr int R_MV    = 2624;              // 1792 (mv rows then pp rows)
constexpr int R_LV    = 4416;              // 101: bits(lv)@W_level + (lv/100)W_feats[0]
constexpr int R_HP    = 4517;              // 1024: bits(hp)@W_hp + (hp/1023)W_feats[1]
constexpr int R_VOL   = 5541;              // 4*256 pair tables + 16 single = 1040
constexpr int R_BST   = 6581;              // 3*169 pair tables + 13 single = 520
constexpr int R_GS    = 7101;              // 32: gender x status
constexpr int R_FLAGS = 7133;              // 32: cb,trap,newsw,faint,active bits
constexpr int R_TS    = 7165;              // 32: toxic x sleep
constexpr int R_TOTAL = 7197;
constexpr size_t WS_NEED = (size_t)R_TOTAL * D_DIM * sizeof(unsigned short);

__device__ inline unsigned short f2bf(float f) {      // round-to-nearest-even
    unsigned u = __float_as_uint(f);
    u += 0x7fffu + ((u >> 16) & 1u);
    return (unsigned short)(u >> 16);
}

// ---------------- table precompute: 1 row per block, 2 dims per thread ----------------
__global__ __launch_bounds__(256) void build_tables(
    const float* __restrict__ Wsp, const float* __restrict__ bsp,
    const float* __restrict__ Wab, const float* __restrict__ bab,
    const float* __restrict__ Wit, const float* __restrict__ bit_,
    const float* __restrict__ Wmv, const float* __restrict__ bmv,
    const float* __restrict__ Wlv, const float* __restrict__ blv,
    const float* __restrict__ Whp, const float* __restrict__ bhp,
    const float* __restrict__ Wvo, const float* __restrict__ bvo,
    const float* __restrict__ Wft, const float* __restrict__ bft,
    const float* __restrict__ Wbo, const float* __restrict__ bbo,
    unsigned short* __restrict__ T)
{
    const int r = blockIdx.x;
    const int d = threadIdx.x << 1;
    float vx = 0.f, vy = 0.f;
    auto add = [&](const float* W, int row, float s) {
        const float2 w = *reinterpret_cast<const float2*>(W + (size_t)row * D_DIM + d);
        vx = fmaf(s, w.x, vx); vy = fmaf(s, w.y, vy);
    };
    if (r < R_AB) {
        add(Wsp, r, 1.f);
        add(bsp, 0, 1.f); add(bab, 0, 1.f); add(bit_, 0, 1.f);
        add(bmv, 0, 1.f); add(blv, 0, 1.f); add(bhp, 0, 1.f);
        add(bvo, 0, 1.f); add(bft, 0, 1.f); add(bbo, 0, 1.f);
    } else if (r < R_IT) {
        add(Wab, r - R_AB, 1.f);
    } else if (r < R_MV) {
        add(Wit, r - R_IT, 1.f);
    } else if (r < R_LV) {
        add(Wmv, r - R_MV, 1.f);
    } else if (r < R_HP) {
        const int lv = r - R_LV;
        for (int b = 0; b < 7; ++b) if ((lv >> b) & 1) add(Wlv, b, 1.f);
        add(Wft, 0, (float)lv * (1.f / 100.f));
    } else if (r < R_VOL) {
        const int hp = r - R_HP;
        for (int b = 0; b < 10; ++b) if ((hp >> b) & 1) add(Whp, b, 1.f);
        add(Wft, 1, (float)hp * (1.f / 1023.f));
    } else if (r < R_BST) {
        const int rr = r - R_VOL;
        if (rr < 1024) {                       // pair table p: code = v[2p] | v[2p+1]<<4
            const int p = rr >> 8, code = rr & 255, va = code & 15, vb = code >> 4;
            for (int b = 0; b < 4; ++b) {
                if ((va >> b) & 1) add(Wvo, 8 * p + b, 1.f);
                if ((vb >> b) & 1) add(Wvo, 8 * p + 4 + b, 1.f);
            }
        } else {                               // single col 8
            const int code = rr - 1024;
            for (int b = 0; b < 4; ++b) if ((code >> b) & 1) add(Wvo, 32 + b, 1.f);
        }
    } else if (r < R_GS) {
        const int rr = r - R_BST;
        if (rr < 507) {                        // pair q: idx = (b2q+6) + 13*(b2q1+6)
            const int q = rr / 169, code = rr % 169, ba = code % 13, bb = code / 13;
            add(Wbo, 34 + 26 * q + ba, 1.f);
            add(Wbo, 34 + 26 * q + 13 + bb, 1.f);
            add(Wft, 2 + 2 * q, 0.5f * (float)(ba - 6));
            add(Wft, 3 + 2 * q, 0.5f * (float)(bb - 6));
        } else {                               // single boost 6
            const int code = rr - 507;
            add(Wbo, 34 + 78 + code, 1.f);
            add(Wft, 8, 0.5f * (float)(code - 6));
        }
    } else if (r < R_FLAGS) {
        const int code = r - R_GS;             // g*8 + s
        add(Wbo, code >> 3, 1.f);
        add(Wbo, 4 + (code & 7), 1.f);
    } else if (r < R_TS) {
        const int code = r - R_FLAGS;          // cb*16+tr*8+ns*4+fa*2+ac
        add(Wbo, 12 + ((code >> 4) & 1), 1.f);
        add(Wbo, 14 + ((code >> 3) & 1), 1.f);
        add(Wbo, 16 + ((code >> 2) & 1), 1.f);
        add(Wbo, 30 + ((code >> 1) & 1), 1.f);
        add(Wbo, 32 + (code & 1), 1.f);
    } else {
        const int code = r - R_TS;             // tox*4 + sl
        add(Wbo, 18 + (code >> 2), 1.f);
        add(Wbo, 26 + (code & 3), 1.f);
    }
    ushort2 o; o.x = f2bf(vx); o.y = f2bf(vy);
    *reinterpret_cast<ushort2*>(T + (size_t)r * D_DIM + d) = o;
}

// -------- main encode: 1 wave = 1 entity; each load = full 1 KB bf16 row --------
// Row addresses are wave-uniform -> SALU + saddr loads (zero VALU address math).
// Accumulators are float2 so adds/fmas map to v_pk_add_f32 / v_pk_fma_f32.
__global__ __launch_bounds__(256) void encode_kernel(
    const int* __restrict__ ent, const unsigned short* __restrict__ T,
    float* __restrict__ out_emb, float* __restrict__ out_mask, int n)
{
    const int w = (blockIdx.x << 2) | (threadIdx.x >> 6);   // wave id = entity id
    if (w >= n) return;
    const int e_idx = __builtin_amdgcn_readfirstlane(w);    // wave-uniform -> SGPR
    const int lane = threadIdx.x & 63;
    const int* __restrict__ e = ent + (size_t)e_idx * ENT_LEN;  // uniform -> s_load
    const char* __restrict__ Tb = reinterpret_cast<const char*>(T);
    const unsigned laneByte = (unsigned)lane << 4;          // 16 B per lane

    f32x2 c0 = {0.f, 0.f}, c1 = {0.f, 0.f}, c2 = {0.f, 0.f}, c3 = {0.f, 0.f};

    auto UNP = [](unsigned u) -> f32x2 {   // lo exact via shift; hi contaminated (<=2^-8 rel)
        f32x2 r; r.x = __uint_as_float(u << 16); r.y = __uint_as_float(u); return r;
    };
    auto ACC = [&](int row) {
        const uint4 u = *reinterpret_cast<const uint4*>(
            Tb + (((size_t)(unsigned)row << 10) + laneByte));
        c0 += UNP(u.x); c1 += UNP(u.y); c2 += UNP(u.z); c3 += UNP(u.w);
    };
    auto FMA = [&](int row, float s) {
        const uint4 u = *reinterpret_cast<const uint4*>(
            Tb + (((size_t)(unsigned)row << 10) + laneByte));
        const f32x2 sv = {s, s};
        c0 = __builtin_elementwise_fma(UNP(u.x), sv, c0);
        c1 = __builtin_elementwise_fma(UNP(u.y), sv, c1);
        c2 = __builtin_elementwise_fma(UNP(u.z), sv, c2);
        c3 = __builtin_elementwise_fma(UNP(u.w), sv, c3);
    };

    const int sp = e[0];
    ACC(R_SP + sp);                        // biases folded here
    ACC(R_AB + e[1]);
    ACC(R_IT + e[2]);
    #pragma unroll
    for (int m = 0; m < 4; ++m) {
        const int mv = e[21 + m];
        ACC(R_MV + mv);
        FMA(R_MV + N_MOVES + mv, (float)e[25 + m] * (1.f / 1023.f));
    }
    ACC(R_LV + e[3]);
    ACC(R_HP + e[4]);
    #pragma unroll
    for (int q = 0; q < 4; ++q)
        ACC(R_VOL + (q << 8) + (e[30 + 2 * q] | (e[31 + 2 * q] << 4)));
    ACC(R_VOL + 1024 + e[38]);
    #pragma unroll
    for (int q = 0; q < 3; ++q)
        ACC(R_BST + q * 169 + (e[14 + 2 * q] + 6) + 13 * (e[15 + 2 * q] + 6));
    ACC(R_BST + 507 + e[20] + 6);
    ACC(R_GS + (e[5] << 3) + e[6]);
    ACC(R_FLAGS + (e[7] << 4) + (e[8] << 3) + (e[9] << 2) + (e[12] << 1) + e[13]);
    ACC(R_TS + (e[10] << 2) + e[11]);

    const float msk = (sp > 1) ? 1.f : 0.f;
    const f32x2 mv2 = {msk, msk};
    c0 *= mv2; c1 *= mv2; c2 *= mv2; c3 *= mv2;

    // lane covers 8 consecutive f32 dims: d = lane*8
    f32x4 o0 = {c0.x, c0.y, c1.x, c1.y};
    f32x4 o1 = {c2.x, c2.y, c3.x, c3.y};
    float* op = out_emb + (size_t)e_idx * D_DIM + ((unsigned)lane << 3);
    __builtin_nontemporal_store(o0, reinterpret_cast<f32x4*>(op));
    __builtin_nontemporal_store(o1, reinterpret_cast<f32x4*>(op + 4));
    if (lane == 0) out_mask[e_idx] = msk;
}

// ---------------- fallback (round-0 kernel) if workspace is too small ----------------
__global__ __launch_bounds__(256) void entity_encoder_fallback(
    const int*   __restrict__ ent,
    const float* __restrict__ W_species, const float* __restrict__ b_species,
    const float* __restrict__ W_ability, const float* __restrict__ b_ability,
    const float* __restrict__ W_item,    const float* __restrict__ b_item,
    const float* __restrict__ W_moveset, const float* __restrict__ b_moveset,
    const float* __restrict__ W_level,   const float* __restrict__ b_level,
    const float* __restrict__ W_hp,      const float* __restrict__ b_hp,
    const float* __restrict__ W_vol,     const float* __restrict__ b_vol,
    const float* __restrict__ W_feats,   const float* __restrict__ b_feats,
    const float* __restrict__ W_bool,    const float* __restrict__ b_bool,
    float* __restrict__ out_emb, float* __restrict__ out_mask, int n)
{
    const int e_idx = (blockIdx.x << 1) | (threadIdx.x >> 7);
    if (e_idx >= n) return;
    const int t = threadIdx.x & 127;
    const int d = t << 2;
    const int* __restrict__ e = ent + e_idx * ENT_LEN;
    float4 acc = make_float4(0.f, 0.f, 0.f, 0.f);
#define ADDROW(W, row) do {                                                        \
        const float4 v_ = *reinterpret_cast<const float4*>((W) + ((size_t)(row))*D_DIM + d); \
        acc.x += v_.x; acc.y += v_.y; acc.z += v_.z; acc.w += v_.w;                \
    } while (0)
#define FMAROW(W, row, s) do {                                                     \
        const float4 v_ = *reinterpret_cast<const float4*>((W) + ((size_t)(row))*D_DIM + d); \
        const float s_ = (s);                                                      \
        acc.x = fmaf(s_, v_.x, acc.x); acc.y = fmaf(s_, v_.y, acc.y);              \
        acc.z = fmaf(s_, v_.z, acc.z); acc.w = fmaf(s_, v_.w, acc.w);              \
    } while (0)
    const int sp = e[0];
    ADDROW(W_species, sp); ADDROW(W_ability, e[1]); ADDROW(W_item, e[2]);
    #pragma unroll
    for (int m = 0; m < 4; ++m) {
        const int mv = e[21 + m];
        ADDROW(W_moveset, mv);
        FMAROW(W_moveset, N_MOVES + mv, (float)e[25 + m] * (1.0f / 1023.0f));
    }
    const int lv = e[3];
    #pragma unroll
    for (int b = 0; b < 7; ++b) if ((lv >> b) & 1) ADDROW(W_level, b);
    const int hp = e[4];
    #pragma unroll
    for (int b = 0; b < 10; ++b) if ((hp >> b) & 1) ADDROW(W_hp, b);
    #pragma unroll
    for (int j = 0; j < 9; ++j) {
        const int v = e[30 + j];
        #pragma unroll
        for (int b = 0; b < 4; ++b) if ((v >> b) & 1) ADDROW(W_vol, j * 4 + b);
    }
    FMAROW(W_feats, 0, (float)lv * (1.0f / 100.0f));
    FMAROW(W_feats, 1, (float)hp * (1.0f / 1023.0f));
    #pragma unroll
    for (int i = 0; i < 7; ++i) FMAROW(W_feats, 2 + i, 0.5f * (float)e[14 + i]);
    ADDROW(W_bool, e[5]); ADDROW(W_bool, 4 + e[6]); ADDROW(W_bool, 12 + e[7]);
    ADDROW(W_bool, 14 + e[8]); ADDROW(W_bool, 16 + e[9]); ADDROW(W_bool, 18 + e[10]);
    ADDROW(W_bool, 26 + e[11]); ADDROW(W_bool, 30 + e[12]); ADDROW(W_bool, 32 + e[13]);
    #pragma unroll
    for (int i = 0; i < 7; ++i) ADDROW(W_bool, 34 + 13 * i + e[14 + i] + 6);
    ADDROW(b_species, 0); ADDROW(b_ability, 0); ADDROW(b_item, 0);
    ADDROW(b_moveset, 0); ADDROW(b_level, 0);   ADDROW(b_hp, 0);
    ADDROW(b_vol, 0);     ADDROW(b_feats, 0);   ADDROW(b_bool, 0);
#undef ADDROW
#undef FMAROW
    const bool mask = !(sp == 0 || sp == 1);
    if (!mask) acc = make_float4(0.f, 0.f, 0.f, 0.f);
    *reinterpret_cast<float4*>(out_emb + (size_t)e_idx * D_DIM + d) = acc;
    if (t == 0) out_mask[e_idx] = mask ? 1.0f : 0.0f;
}

} // namespace

extern "C" void kernel_launch(void* const* d_in, const int* in_sizes, int n_in,
                              void* d_out, int out_size, void* d_ws, size_t ws_size,
                              hipStream_t stream) {
    const int n = in_sizes[0] / ENT_LEN;

    const int*   ent  = (const int*)  d_in[0];
    const float* Wsp  = (const float*)d_in[1];
    const float* bsp  = (const float*)d_in[2];
    const float* Wab  = (const float*)d_in[3];
    const float* bab  = (const float*)d_in[4];
    const float* Wit  = (const float*)d_in[5];
    const float* bit_ = (const float*)d_in[6];
    const float* Wmv  = (const float*)d_in[7];
    const float* bmv  = (const float*)d_in[8];
    const float* Wlv  = (const float*)d_in[9];
    const float* blv  = (const float*)d_in[10];
    const float* Whp  = (const float*)d_in[11];
    const float* bhp  = (const float*)d_in[12];
    const float* Wvo  = (const float*)d_in[13];
    const float* bvo  = (const float*)d_in[14];
    const float* Wft  = (const float*)d_in[15];
    const float* bft  = (const float*)d_in[16];
    const float* Wbo  = (const float*)d_in[17];
    const float* bbo  = (const float*)d_in[18];

    float* out_emb  = (float*)d_out;
    float* out_mask = out_emb + (size_t)n * D_DIM;

    if (ws_size >= WS_NEED) {
        unsigned short* T = (unsigned short*)d_ws;
        build_tables<<<R_TOTAL, 256, 0, stream>>>(
            Wsp, bsp, Wab, bab, Wit, bit_, Wmv, bmv, Wlv, blv,
            Whp, bhp, Wvo, bvo, Wft, bft, Wbo, bbo, T);
        encode_kernel<<<(n + 3) / 4, 256, 0, stream>>>(ent, T, out_emb, out_mask, n);
    } else {
        entity_encoder_fallback<<<(n + 1) / 2, 256, 0, stream>>>(
            ent, Wsp, bsp, Wab, bab, Wit, bit_, Wmv, bmv, Wlv, blv,
            Whp, bhp, Wvo, bvo, Wft, bft, Wbo, bbo, out_emb, out_mask, n);
    }
}

// Round 6
// 100.064 us; speedup vs baseline: 1.0316x; 1.0316x over previous
//
#include <hip/hip_runtime.h>

namespace {

constexpr int D_DIM   = 512;
constexpr int ENT_LEN = 39;

typedef __attribute__((ext_vector_type(4))) float f32x4;
typedef __attribute__((ext_vector_type(2))) float f32x2;

// ---- fused bf16 table row offsets (logical rows of 512 bf16 = 1 KB each) ----
constexpr int R_SP    = 0;                 // 1280 rows: W_species[r] + sum(all 9 biases)
constexpr int R_AB    = 1280;              // 320
constexpr int R_IT    = 1600;              // 1024
constexpr int R_MV    = 2624;              // 1792: PHYSICALLY re-laid as 896 moves x 2 KB,
                                           //   block (2m+h) = interleaved mv/pp 8B chunks
constexpr int R_LV    = 4416;              // 101: bits(lv)@W_level + (lv/100)W_feats[0]
constexpr int R_HP    = 4517;              // 1024: bits(hp)@W_hp + (hp/1023)W_feats[1]
constexpr int R_VOL   = 5541;              // 4*256 pair tables + 16 single = 1040
constexpr int R_BST   = 6581;              // 3*169 pair tables + 13 single = 520
constexpr int R_GS    = 7101;              // 32: gender x status
constexpr int R_FLAGS = 7133;              // 32: cb,trap,newsw,faint,active bits
constexpr int R_TS    = 7165;              // 32: toxic x sleep
constexpr int R_TOTAL = 7197;
constexpr size_t WS_NEED = (size_t)R_TOTAL * D_DIM * sizeof(unsigned short);

__device__ inline unsigned short f2bf(float f) {      // round-to-nearest-even
    unsigned u = __float_as_uint(f);
    u += 0x7fffu + ((u >> 16) & 1u);
    return (unsigned short)(u >> 16);
}

// ---------------- table precompute: 1 logical row per block, 2 dims per thread ----------------
__global__ __launch_bounds__(256) void build_tables(
    const float* __restrict__ Wsp, const float* __restrict__ bsp,
    const float* __restrict__ Wab, const float* __restrict__ bab,
    const float* __restrict__ Wit, const float* __restrict__ bit_,
    const float* __restrict__ Wmv, const float* __restrict__ bmv,
    const float* __restrict__ Wlv, const float* __restrict__ blv,
    const float* __restrict__ Whp, const float* __restrict__ bhp,
    const float* __restrict__ Wvo, const float* __restrict__ bvo,
    const float* __restrict__ Wft, const float* __restrict__ bft,
    const float* __restrict__ Wbo, const float* __restrict__ bbo,
    unsigned short* __restrict__ T)
{
    const int r = blockIdx.x;
    const int d = threadIdx.x << 1;
    float vx = 0.f, vy = 0.f;
    auto add = [&](const float* W, int row, float s) {
        const float2 w = *reinterpret_cast<const float2*>(W + (size_t)row * D_DIM + d);
        vx = fmaf(s, w.x, vx); vy = fmaf(s, w.y, vy);
    };
    if (r < R_AB) {
        add(Wsp, r, 1.f);
        add(bsp, 0, 1.f); add(bab, 0, 1.f); add(bit_, 0, 1.f);
        add(bmv, 0, 1.f); add(blv, 0, 1.f); add(bhp, 0, 1.f);
        add(bvo, 0, 1.f); add(bft, 0, 1.f); add(bbo, 0, 1.f);
    } else if (r < R_IT) {
        add(Wab, r - R_AB, 1.f);
    } else if (r < R_MV) {
        add(Wit, r - R_IT, 1.f);
    } else if (r < R_LV) {
        add(Wmv, r - R_MV, 1.f);             // rows 0..895 = mv, 896..1791 = pp
    } else if (r < R_HP) {
        const int lv = r - R_LV;
        for (int b = 0; b < 7; ++b) if ((lv >> b) & 1) add(Wlv, b, 1.f);
        add(Wft, 0, (float)lv * (1.f / 100.f));
    } else if (r < R_VOL) {
        const int hp = r - R_HP;
        for (int b = 0; b < 10; ++b) if ((hp >> b) & 1) add(Whp, b, 1.f);
        add(Wft, 1, (float)hp * (1.f / 1023.f));
    } else if (r < R_BST) {
        const int rr = r - R_VOL;
        if (rr < 1024) {                       // pair table p: code = v[2p] | v[2p+1]<<4
            const int p = rr >> 8, code = rr & 255, va = code & 15, vb = code >> 4;
            for (int b = 0; b < 4; ++b) {
                if ((va >> b) & 1) add(Wvo, 8 * p + b, 1.f);
                if ((vb >> b) & 1) add(Wvo, 8 * p + 4 + b, 1.f);
            }
        } else {                               // single col 8
            const int code = rr - 1024;
            for (int b = 0; b < 4; ++b) if ((code >> b) & 1) add(Wvo, 32 + b, 1.f);
        }
    } else if (r < R_GS) {
        const int rr = r - R_BST;
        if (rr < 507) {                        // pair q: idx = (b2q+6) + 13*(b2q1+6)
            const int q = rr / 169, code = rr % 169, ba = code % 13, bb = code / 13;
            add(Wbo, 34 + 26 * q + ba, 1.f);
            add(Wbo, 34 + 26 * q + 13 + bb, 1.f);
            add(Wft, 2 + 2 * q, 0.5f * (float)(ba - 6));
            add(Wft, 3 + 2 * q, 0.5f * (float)(bb - 6));
        } else {                               // single boost 6
            const int code = rr - 507;
            add(Wbo, 34 + 78 + code, 1.f);
            add(Wft, 8, 0.5f * (float)(code - 6));
        }
    } else if (r < R_FLAGS) {
        const int code = r - R_GS;             // g*8 + s
        add(Wbo, code >> 3, 1.f);
        add(Wbo, 4 + (code & 7), 1.f);
    } else if (r < R_TS) {
        const int code = r - R_FLAGS;          // cb*16+tr*8+ns*4+fa*2+ac
        add(Wbo, 12 + ((code >> 4) & 1), 1.f);
        add(Wbo, 14 + ((code >> 3) & 1), 1.f);
        add(Wbo, 16 + ((code >> 2) & 1), 1.f);
        add(Wbo, 30 + ((code >> 1) & 1), 1.f);
        add(Wbo, 32 + (code & 1), 1.f);
    } else {
        const int code = r - R_TS;             // tox*4 + sl
        add(Wbo, 18 + (code >> 2), 1.f);
        add(Wbo, 26 + (code & 3), 1.f);
    }

    // physical store index (ushorts). Default: logical row-major.
    size_t sidx = (size_t)r * D_DIM + d;
    if (r >= R_MV && r < R_LV) {
        // mvpp swizzle: block (2m+h) of 1 KB; lane chunk 16B = [mv 8B | pp 8B] for dims 4l..4l+3
        const int cr  = r - R_MV;
        const int tau = (cr >= 896) ? 1 : 0;   // 0 = mv content, 1 = pp content
        const int m   = cr - tau * 896;
        const int h   = d >> 8, l = (d & 255) >> 2, sub = d & 3;
        sidx = ((size_t)(R_MV + 2 * m + h) << 9) + (l << 3) + (tau << 2) + sub;
    }
    ushort2 o; o.x = f2bf(vx); o.y = f2bf(vy);
    *reinterpret_cast<ushort2*>(T + sidx) = o;
}

// -------- main encode: 1 wave = (entity, D-half); all 21 loads issued before accumulation --------
// Row bases are wave-uniform -> SALU + saddr loads. Half-0 waves dispatch first:
// live table working set ~3.7 MB < 4 MB per-XCD L2.
__global__ __launch_bounds__(256, 4) void encode_kernel(
    const int* __restrict__ ent, const unsigned short* __restrict__ T,
    float* __restrict__ out_emb, float* __restrict__ out_mask, int n)
{
    const int w = (blockIdx.x << 2) | (threadIdx.x >> 6);   // wave id in [0, 2n)
    const int half = (w >= n) ? 1 : 0;
    const int ew = w - (half ? n : 0);
    if (ew >= n) return;
    const int e_idx = __builtin_amdgcn_readfirstlane(ew);   // wave-uniform -> SGPR
    const int lane = threadIdx.x & 63;
    const int* __restrict__ e = ent + (size_t)e_idx * ENT_LEN;  // uniform -> s_load
    const char* __restrict__ Tb = reinterpret_cast<const char*>(T);
    const unsigned halfByte = (unsigned)half << 9;
    const unsigned off2 = (unsigned)lane << 3;              // 8 B per lane (uint2 rows)
    const unsigned off4 = (unsigned)lane << 4;              // 16 B per lane (mvpp rows)

    auto LD2 = [&](int row) -> uint2 {
        return *reinterpret_cast<const uint2*>(
            Tb + (((unsigned)row << 10) + halfByte) + off2);
    };
    auto LD4 = [&](int mv) -> uint4 {                        // mvpp fused block
        return *reinterpret_cast<const uint4*>(
            Tb + ((unsigned)(R_MV + 2 * mv + half) << 10) + off4);
    };

    // ---- all row indices (SALU) ----
    const int sp = e[0];
    const int mv0 = e[21], mv1 = e[22], mv2 = e[23], mv3 = e[24];

    // ---- issue ALL loads into named registers (keeps ~21 loads in flight) ----
    const uint2 uSP = LD2(R_SP + sp);
    const uint2 uAB = LD2(R_AB + e[1]);
    const uint2 uIT = LD2(R_IT + e[2]);
    const uint4 uM0 = LD4(mv0);
    const uint4 uM1 = LD4(mv1);
    const uint4 uM2 = LD4(mv2);
    const uint4 uM3 = LD4(mv3);
    const uint2 uLV = LD2(R_LV + e[3]);
    const uint2 uHP = LD2(R_HP + e[4]);
    const uint2 uV0 = LD2(R_VOL + (0 << 8) + (e[30] | (e[31] << 4)));
    const uint2 uV1 = LD2(R_VOL + (1 << 8) + (e[32] | (e[33] << 4)));
    const uint2 uV2 = LD2(R_VOL + (2 << 8) + (e[34] | (e[35] << 4)));
    const uint2 uV3 = LD2(R_VOL + (3 << 8) + (e[36] | (e[37] << 4)));
    const uint2 uV4 = LD2(R_VOL + 1024 + e[38]);
    const uint2 uB0 = LD2(R_BST + 0 * 169 + (e[14] + 6) + 13 * (e[15] + 6));
    const uint2 uB1 = LD2(R_BST + 1 * 169 + (e[16] + 6) + 13 * (e[17] + 6));
    const uint2 uB2 = LD2(R_BST + 2 * 169 + (e[18] + 6) + 13 * (e[19] + 6));
    const uint2 uB3 = LD2(R_BST + 507 + e[20] + 6);
    const uint2 uGS = LD2(R_GS + (e[5] << 3) + e[6]);
    const uint2 uFL = LD2(R_FLAGS + (e[7] << 4) + (e[8] << 3) + (e[9] << 2) +
                          (e[12] << 1) + e[13]);
    const uint2 uTS = LD2(R_TS + (e[10] << 2) + e[11]);

    const float s0 = (float)e[25] * (1.f / 1023.f);
    const float s1 = (float)e[26] * (1.f / 1023.f);
    const float s2 = (float)e[27] * (1.f / 1023.f);
    const float s3 = (float)e[28] * (1.f / 1023.f);

    // ---- accumulate (lane covers dims half*256 + lane*4 .. +3) ----
    f32x2 c0 = {0.f, 0.f}, c1 = {0.f, 0.f};
    auto UNP = [](unsigned u) -> f32x2 {   // lo exact via shift; hi contaminated (<=2^-8 rel)
        f32x2 r; r.x = __uint_as_float(u << 16); r.y = __uint_as_float(u); return r;
    };
    auto A2 = [&](uint2 u) { c0 += UNP(u.x); c1 += UNP(u.y); };
    auto AM = [&](uint4 u, float s) {
        c0 += UNP(u.x); c1 += UNP(u.y);
        const f32x2 sv = {s, s};
        c0 = __builtin_elementwise_fma(UNP(u.z), sv, c0);
        c1 = __builtin_elementwise_fma(UNP(u.w), sv, c1);
    };

    A2(uSP); A2(uAB); A2(uIT);
    AM(uM0, s0); AM(uM1, s1); AM(uM2, s2); AM(uM3, s3);
    A2(uLV); A2(uHP);
    A2(uV0); A2(uV1); A2(uV2); A2(uV3); A2(uV4);
    A2(uB0); A2(uB1); A2(uB2); A2(uB3);
    A2(uGS); A2(uFL); A2(uTS);

    const float msk = (sp > 1) ? 1.f : 0.f;
    const f32x2 mk = {msk, msk};
    c0 *= mk; c1 *= mk;

    f32x4 o = {c0.x, c0.y, c1.x, c1.y};
    float* op = out_emb + (size_t)e_idx * D_DIM + (halfByte >> 1) + ((unsigned)lane << 2);
    __builtin_nontemporal_store(o, reinterpret_cast<f32x4*>(op));
    if (half == 0 && lane == 0) out_mask[e_idx] = msk;
}

// ---------------- fallback (round-0 kernel) if workspace is too small ----------------
__global__ __launch_bounds__(256) void entity_encoder_fallback(
    const int*   __restrict__ ent,
    const float* __restrict__ W_species, const float* __restrict__ b_species,
    const float* __restrict__ W_ability, const float* __restrict__ b_ability,
    const float* __restrict__ W_item,    const float* __restrict__ b_item,
    const float* __restrict__ W_moveset, const float* __restrict__ b_moveset,
    const float* __restrict__ W_level,   const float* __restrict__ b_level,
    const float* __restrict__ W_hp,      const float* __restrict__ b_hp,
    const float* __restrict__ W_vol,     const float* __restrict__ b_vol,
    const float* __restrict__ W_feats,   const float* __restrict__ b_feats,
    const float* __restrict__ W_bool,    const float* __restrict__ b_bool,
    float* __restrict__ out_emb, float* __restrict__ out_mask, int n)
{
    const int e_idx = (blockIdx.x << 1) | (threadIdx.x >> 7);
    if (e_idx >= n) return;
    const int t = threadIdx.x & 127;
    const int d = t << 2;
    const int* __restrict__ e = ent + e_idx * ENT_LEN;
    float4 acc = make_float4(0.f, 0.f, 0.f, 0.f);
#define ADDROW(W, row) do {                                                        \
        const float4 v_ = *reinterpret_cast<const float4*>((W) + ((size_t)(row))*D_DIM + d); \
        acc.x += v_.x; acc.y += v_.y; acc.z += v_.z; acc.w += v_.w;                \
    } while (0)
#define FMAROW(W, row, s) do {                                                     \
        const float4 v_ = *reinterpret_cast<const float4*>((W) + ((size_t)(row))*D_DIM + d); \
        const float s_ = (s);                                                      \
        acc.x = fmaf(s_, v_.x, acc.x); acc.y = fmaf(s_, v_.y, acc.y);              \
        acc.z = fmaf(s_, v_.z, acc.z); acc.w = fmaf(s_, v_.w, acc.w);              \
    } while (0)
    const int sp = e[0];
    ADDROW(W_species, sp); ADDROW(W_ability, e[1]); ADDROW(W_item, e[2]);
    #pragma unroll
    for (int m = 0; m < 4; ++m) {
        const int mv = e[21 + m];
        ADDROW(W_moveset, mv);
        FMAROW(W_moveset, 896 + mv, (float)e[25 + m] * (1.0f / 1023.0f));
    }
    const int lv = e[3];
    #pragma unroll
    for (int b = 0; b < 7; ++b) if ((lv >> b) & 1) ADDROW(W_level, b);
    const int hp = e[4];
    #pragma unroll
    for (int b = 0; b < 10; ++b) if ((hp >> b) & 1) ADDROW(W_hp, b);
    #pragma unroll
    for (int j = 0; j < 9; ++j) {
        const int v = e[30 + j];
        #pragma unroll
        for (int b = 0; b < 4; ++b) if ((v >> b) & 1) ADDROW(W_vol, j * 4 + b);
    }
    FMAROW(W_feats, 0, (float)lv * (1.0f / 100.0f));
    FMAROW(W_feats, 1, (float)hp * (1.0f / 1023.0f));
    #pragma unroll
    for (int i = 0; i < 7; ++i) FMAROW(W_feats, 2 + i, 0.5f * (float)e[14 + i]);
    ADDROW(W_bool, e[5]); ADDROW(W_bool, 4 + e[6]); ADDROW(W_bool, 12 + e[7]);
    ADDROW(W_bool, 14 + e[8]); ADDROW(W_bool, 16 + e[9]); ADDROW(W_bool, 18 + e[10]);
    ADDROW(W_bool, 26 + e[11]); ADDROW(W_bool, 30 + e[12]); ADDROW(W_bool, 32 + e[13]);
    #pragma unroll
    for (int i = 0; i < 7; ++i) ADDROW(W_bool, 34 + 13 * i + e[14 + i] + 6);
    ADDROW(b_species, 0); ADDROW(b_ability, 0); ADDROW(b_item, 0);
    ADDROW(b_moveset, 0); ADDROW(b_level, 0);   ADDROW(b_hp, 0);
    ADDROW(b_vol, 0);     ADDROW(b_feats, 0);   ADDROW(b_bool, 0);
#undef ADDROW
#undef FMAROW
    const bool mask = !(sp == 0 || sp == 1);
    if (!mask) acc = make_float4(0.f, 0.f, 0.f, 0.f);
    *reinterpret_cast<float4*>(out_emb + (size_t)e_idx * D_DIM + d) = acc;
    if (t == 0) out_mask[e_idx] = mask ? 1.0f : 0.0f;
}

} // namespace

extern "C" void kernel_launch(void* const* d_in, const int* in_sizes, int n_in,
                              void* d_out, int out_size, void* d_ws, size_t ws_size,
                              hipStream_t stream) {
    const int n = in_sizes[0] / ENT_LEN;

    const int*   ent  = (const int*)  d_in[0];
    const float* Wsp  = (const float*)d_in[1];
    const float* bsp  = (const float*)d_in[2];
    const float* Wab  = (const float*)d_in[3];
    const float* bab  = (const float*)d_in[4];
    const float* Wit  = (const float*)d_in[5];
    const float* bit_ = (const float*)d_in[6];
    const float* Wmv  = (const float*)d_in[7];
    const float* bmv  = (const float*)d_in[8];
    const float* Wlv  = (const float*)d_in[9];
    const float* blv  = (const float*)d_in[10];
    const float* Whp  = (const float*)d_in[11];
    const float* bhp  = (const float*)d_in[12];
    const float* Wvo  = (const float*)d_in[13];
    const float* bvo  = (const float*)d_in[14];
    const float* Wft  = (const float*)d_in[15];
    const float* bft  = (const float*)d_in[16];
    const float* Wbo  = (const float*)d_in[17];
    const float* bbo  = (const float*)d_in[18];

    float* out_emb  = (float*)d_out;
    float* out_mask = out_emb + (size_t)n * D_DIM;

    if (ws_size >= WS_NEED) {
        unsigned short* T = (unsigned short*)d_ws;
        build_tables<<<R_TOTAL, 256, 0, stream>>>(
            Wsp, bsp, Wab, bab, Wit, bit_, Wmv, bmv, Wlv, blv,
            Whp, bhp, Wvo, bvo, Wft, bft, Wbo, bbo, T);
        const int waves = 2 * n;                       // (entity, half)
        encode_kernel<<<(waves + 3) / 4, 256, 0, stream>>>(ent, T, out_emb, out_mask, n);
    } else {
        entity_encoder_fallback<<<(n + 1) / 2, 256, 0, stream>>>(
            ent, Wsp, bsp, Wab, bab, Wit, bit_, Wmv, bmv, Wlv, blv,
            Whp, bhp, Wvo, bvo, Wft, bft, Wbo, bbo, out_emb, out_mask, n);
    }
}